// Round 3
// baseline (210.014 us; speedup 1.0000x reference)
//
#include <hip/hip_runtime.h>
#include <math.h>

#define T_ 128
#define B_ 512
#define S_ 128
#define D_ 128
#define V_ 50257

#define K2_VT 64
#define K2_NB ((V_ + K2_VT - 1) / K2_VT)   // 786

// ---------------- k1: M2[k][s] = sum_d transform[k][d] * tag_embed[s][d] ----------------
__global__ __launch_bounds__(128) void k1_m2(const float* __restrict__ transform,
                                             const float* __restrict__ tag_embed,
                                             float* __restrict__ M2) {
  __shared__ float te[128][129];
  int tid = threadIdx.x;
  for (int r = 0; r < 128; ++r) te[r][tid] = tag_embed[r * 128 + tid];
  __syncthreads();
  int k = blockIdx.x;
  float acc = 0.f;
  #pragma unroll 8
  for (int d = 0; d < 128; ++d) acc += transform[k * 128 + d] * te[tid][d];
  M2[k * 128 + tid] = acc;
}

// ---------------- k1b: A = softmax(tparams, axis=1) ----------------
__global__ __launch_bounds__(64) void k1b_a(const float* __restrict__ tparams,
                                            float* __restrict__ A) {
  int i = blockIdx.x;
  int l = threadIdx.x;
  float x0 = tparams[i * 128 + l];
  float x1 = tparams[i * 128 + 64 + l];
  float m = fmaxf(x0, x1);
  #pragma unroll
  for (int off = 32; off; off >>= 1) m = fmaxf(m, __shfl_xor(m, off));
  float e0 = __expf(x0 - m), e1 = __expf(x1 - m);
  float s = e0 + e1;
  #pragma unroll
  for (int off = 32; off; off >>= 1) s += __shfl_xor(s, off);
  float inv = 1.f / s;
  A[i * 128 + l]      = e0 * inv;
  A[i * 128 + 64 + l] = e1 * inv;
}

// ---------------- k2: logits = we @ M2 + corr^T, fused col-softmax partials ----------------
// 256 threads: sc = tid&31 (s = 4sc+e), vg = tid>>5 (v = v0 + 8vg + u)
// weT: transposed we-tile [d][v] in LDS; M2 staged in 2 chunks of 64 rows.
__global__ __launch_bounds__(256, 2) void k2_logits(const float* __restrict__ we,
                                                 const float* __restrict__ M2,
                                                 const float* __restrict__ corr,
                                                 float* __restrict__ logits,
                                                 float* __restrict__ pmaxb,
                                                 float* __restrict__ psumb) {
  int tid = threadIdx.x;
  int sc = tid & 31;
  int vg = tid >> 5;                // 0..7
  long v0 = (long)blockIdx.x * K2_VT;
  __shared__ float weT[128][68];    // [d][v], +4 pad (keeps 16B alignment, spreads banks)
  __shared__ float m2t[64][128];    // M2 chunk; reused as partial scratch at the end

  // stage + transpose we-tile: read we[v][d] coalesced, write weT[d][v]
  #pragma unroll
  for (int it = 0; it < 32; ++it) {
    int idx = it * 256 + tid;
    int d = idx & 127;
    int vv = idx >> 7;              // 0..63
    long v = v0 + vv;
    weT[d][vv] = (v < V_) ? we[v * 128 + d] : 0.f;
  }

  float acc[8][4];
  #pragma unroll
  for (int u = 0; u < 8; ++u)
    #pragma unroll
    for (int e = 0; e < 4; ++e) acc[u][e] = 0.f;

  #pragma unroll
  for (int c = 0; c < 2; ++c) {
    __syncthreads();                // weT staged (c=0) / prev chunk consumed (c=1)
    #pragma unroll
    for (int it = 0; it < 32; ++it) {
      int idx = it * 256 + tid;
      int kr = idx >> 7, s = idx & 127;
      m2t[kr][s] = M2[(c * 64 + kr) * 128 + s];
    }
    __syncthreads();
    #pragma unroll 8
    for (int k = 0; k < 64; ++k) {
      float4 mv = *(const float4*)&m2t[k][4 * sc];
      float4 w0 = *(const float4*)&weT[c * 64 + k][8 * vg];
      float4 w1 = *(const float4*)&weT[c * 64 + k][8 * vg + 4];
      acc[0][0] += w0.x * mv.x; acc[0][1] += w0.x * mv.y; acc[0][2] += w0.x * mv.z; acc[0][3] += w0.x * mv.w;
      acc[1][0] += w0.y * mv.x; acc[1][1] += w0.y * mv.y; acc[1][2] += w0.y * mv.z; acc[1][3] += w0.y * mv.w;
      acc[2][0] += w0.z * mv.x; acc[2][1] += w0.z * mv.y; acc[2][2] += w0.z * mv.z; acc[2][3] += w0.z * mv.w;
      acc[3][0] += w0.w * mv.x; acc[3][1] += w0.w * mv.y; acc[3][2] += w0.w * mv.z; acc[3][3] += w0.w * mv.w;
      acc[4][0] += w1.x * mv.x; acc[4][1] += w1.x * mv.y; acc[4][2] += w1.x * mv.z; acc[4][3] += w1.x * mv.w;
      acc[5][0] += w1.y * mv.x; acc[5][1] += w1.y * mv.y; acc[5][2] += w1.y * mv.z; acc[5][3] += w1.y * mv.w;
      acc[6][0] += w1.z * mv.x; acc[6][1] += w1.z * mv.y; acc[6][2] += w1.z * mv.z; acc[6][3] += w1.z * mv.w;
      acc[7][0] += w1.w * mv.x; acc[7][1] += w1.w * mv.y; acc[7][2] += w1.w * mv.z; acc[7][3] += w1.w * mv.w;
    }
  }

  // epilogue: + corr, online column partials over this thread's 8 v, float4 stores
  float lm[4], ls[4], Lst[8][4];
  #pragma unroll
  for (int e = 0; e < 4; ++e) { lm[e] = -INFINITY; ls[e] = 0.f; }
  long vbase = v0 + 8 * vg;
  #pragma unroll
  for (int e = 0; e < 4; ++e) {
    long rbase = (long)(4 * sc + e) * V_ + vbase;
    #pragma unroll
    for (int u = 0; u < 8; ++u) {
      if (vbase + u < V_) {
        float L = acc[u][e] + corr[rbase + u];
        Lst[u][e] = L;
        float nm = fmaxf(lm[e], L);
        ls[e] = ls[e] * __expf(lm[e] - nm) + __expf(L - nm);
        lm[e] = nm;
      }
    }
  }
  #pragma unroll
  for (int u = 0; u < 8; ++u) {
    long v = vbase + u;
    if (v < V_) {
      float4 st = make_float4(Lst[u][0], Lst[u][1], Lst[u][2], Lst[u][3]);
      *(float4*)&logits[v * 128 + 4 * sc] = st;
    }
  }

  __syncthreads();                  // m2t reads done -> reuse as scratch
  float* pmx = (float*)m2t;         // [8][128]
  float* psm = pmx + 8 * 128;
  #pragma unroll
  for (int e = 0; e < 4; ++e) {
    pmx[vg * 128 + 4 * sc + e] = lm[e];
    psm[vg * 128 + 4 * sc + e] = ls[e];
  }
  __syncthreads();
  if (tid < 128) {
    int s = tid;
    float m = -INFINITY, sum = 0.f;
    #pragma unroll
    for (int g = 0; g < 8; ++g) {
      float pm = pmx[g * 128 + s];
      if (pm > -1e30f) {
        float ps = psm[g * 128 + s];
        float nm = fmaxf(m, pm);
        sum = sum * __expf(m - nm) + ps * __expf(pm - nm);
        m = nm;
      }
    }
    pmaxb[blockIdx.x * 128 + s] = m;
    psumb[blockIdx.x * 128 + s] = sum;
  }
}

// ---------------- k3: reduce per-block partials -> C[s] ----------------
__global__ __launch_bounds__(256) void k3_c(const float* __restrict__ pmaxb,
                                            const float* __restrict__ psumb,
                                            float* __restrict__ C) {
  int s = blockIdx.x;
  int t = threadIdx.x;
  float m = -INFINITY, sum = 0.f;
  #pragma unroll
  for (int q = 0; q < 4; ++q) {
    int b = t + q * 256;
    if (b < K2_NB) {
      float pm = pmaxb[b * 128 + s];
      if (pm > -1e30f) {
        float ps = psumb[b * 128 + s];
        float nm = fmaxf(m, pm);
        sum = sum * __expf(m - nm) + ps * __expf(pm - nm);
        m = nm;
      }
    }
  }
  #pragma unroll
  for (int off = 32; off; off >>= 1) {
    float om = __shfl_xor(m, off);
    float os = __shfl_xor(sum, off);
    float nm = fmaxf(m, om);
    sum = sum * __expf(m - nm) + os * __expf(om - nm);
    m = nm;
  }
  __shared__ float wm[4], wsv[4];
  int lane = t & 63, wv = t >> 6;
  if (lane == 0) { wm[wv] = m; wsv[wv] = sum; }
  __syncthreads();
  if (t == 0) {
    float M = fmaxf(fmaxf(wm[0], wm[1]), fmaxf(wm[2], wm[3]));
    float S = wsv[0] * __expf(wm[0] - M) + wsv[1] * __expf(wm[1] - M)
            + wsv[2] * __expf(wm[2] - M) + wsv[3] * __expf(wm[3] - M);
    C[s] = M + __logf(S);
  }
}

// ---------------- k4: per-batch forward recurrence, ONE WAVE per batch ----------------
// 64 threads/block = 1 wave, 512 blocks (one per batch). Lane l owns states
// j0 = l and j1 = l + 64. The whole transition matrix lives in registers
// (Ac0[128] + Ac1[128] = 256 VGPRs; __launch_bounds__(64,1) -> 512-VGPR budget).
// els is broadcast to all lanes via 32 uniform-address ds_read_b128 (conflict-free
// broadcast); all reductions are 6-step shfl_xor butterflies. ZERO barriers ->
// no vmcnt/lgkmcnt drain, so the logits gather prefetches 1 iteration ahead and
// its ~500cy L3 latency hides under the 256-FMA dot. The 8-wave version spent
// ~75% of each iteration on barrier arrival + cross-wave LDS round-trips
// (2340 cy/iter measured vs ~500 cy of issue work); this removes all of it.
// Numerics are bit-identical: same chain-of-8 / pairwise-combine dot association,
// same em/blend/rescale formulas, fmax reductions are order-free, and the final
// butterflies match the old per-wave sum association exactly.
#define CHAIN8(EA, EB, AC, B) \
  (EA.x * AC[B] + EA.y * AC[(B)+1] + EA.z * AC[(B)+2] + EA.w * AC[(B)+3] + \
   EB.x * AC[(B)+4] + EB.y * AC[(B)+5] + EB.z * AC[(B)+6] + EB.w * AC[(B)+7])

#define DOT_H(H, G0, G1) { \
  float4 x0 = ELS4[(H)*8+0]; float4 x1 = ELS4[(H)*8+1]; \
  float4 x2 = ELS4[(H)*8+2]; float4 x3 = ELS4[(H)*8+3]; \
  float4 x4 = ELS4[(H)*8+4]; float4 x5 = ELS4[(H)*8+5]; \
  float4 x6 = ELS4[(H)*8+6]; float4 x7 = ELS4[(H)*8+7]; \
  float p00 = CHAIN8(x0, x1, Ac0, (H)*32+0); \
  float p01 = CHAIN8(x2, x3, Ac0, (H)*32+8); \
  float p02 = CHAIN8(x4, x5, Ac0, (H)*32+16); \
  float p03 = CHAIN8(x6, x7, Ac0, (H)*32+24); \
  float p10 = CHAIN8(x0, x1, Ac1, (H)*32+0); \
  float p11 = CHAIN8(x2, x3, Ac1, (H)*32+8); \
  float p12 = CHAIN8(x4, x5, Ac1, (H)*32+16); \
  float p13 = CHAIN8(x6, x7, Ac1, (H)*32+24); \
  G0 = (p00 + p01) + (p02 + p03); \
  G1 = (p10 + p11) + (p12 + p13); }

__global__ __launch_bounds__(64, 1) void k4_rec(const int* __restrict__ words,
                                                const float* __restrict__ masks,
                                                const float* __restrict__ A,
                                                const float* __restrict__ C,
                                                const float* __restrict__ logits,
                                                float* __restrict__ bv) {
  const float kB = 70.70101247f;     // 102*ln2, pairs with 0x1p102f
  int l = threadIdx.x;               // 0..63
  int b = blockIdx.x;
  __shared__ __align__(16) float els[128];
  __shared__ int   wbuf[128];
  __shared__ float mbuf[128];
  wbuf[l]      = words[l * B_ + b];
  wbuf[l + 64] = words[(l + 64) * B_ + b];
  mbuf[l]      = masks[l * B_ + b];
  mbuf[l + 64] = masks[(l + 64) * B_ + b];

  float Ac0[128], Ac1[128];
  #pragma unroll
  for (int i = 0; i < 128; ++i) {
    Ac0[i] = A[i * 128 + l];
    Ac1[i] = A[i * 128 + 64 + l];
  }
  float Cj0 = C[l], Cj1 = C[l + 64];
  __syncthreads();                   // wbuf/mbuf visible (single-wave barrier, preamble only)

  // ---- t = 0 ----
  int w0 = wbuf[0];
  float a0i = -4.852030263919617f + logits[(unsigned)(w0 * 128 + l)] - Cj0;
  float a1i = -4.852030263919617f + logits[(unsigned)(w0 * 128 + 64 + l)] - Cj1;
  float m0 = a0i, m1 = a1i;
  #pragma unroll
  for (int off = 32; off; off >>= 1) {
    m0 = fmaxf(m0, __shfl_xor(m0, off));
    m1 = fmaxf(m1, __shfl_xor(m1, off));
  }
  float M0 = fmaxf(m0, m1);
  float a0 = __expf(a0i - M0), a1 = __expf(a1i - M0);
  float S = M0;
  els[l] = a0; els[l + 64] = a1;
  float Mst = fmaxf(a0, a1);
  #pragma unroll
  for (int off = 32; off; off >>= 1) Mst = fmaxf(Mst, __shfl_xor(Mst, off));
  // prefetch L for t = 1
  int w1 = wbuf[1];
  float Lc0 = logits[(unsigned)(w1 * 128 + l)];
  float Lc1 = logits[(unsigned)(w1 * 128 + 64 + l)];

  const float4* ELS4 = (const float4*)els;

  for (int t = 1; t < T_; ++t) {
    // prefetch next step's logits row (1-iter distance; no barriers -> no drain)
    int wn = wbuf[(t < T_ - 1) ? (t + 1) : t];
    float Lp0 = logits[(unsigned)(wn * 128 + l)];
    float Lp1 = logits[(unsigned)(wn * 128 + 64 + l)];

    // dot: new[j] = sum_i els[i] * A[i][j], exact old association
    float G00, G01, G02, G03, G10, G11, G12, G13;
    DOT_H(0, G00, G10)
    DOT_H(1, G01, G11)
    DOT_H(2, G02, G12)
    DOT_H(3, G03, G13)
    float P0 = (G00 + G01) + (G02 + G03);
    float P1 = (G10 + G11) + (G12 + G13);

    float em0 = __expf(Lc0 - Cj0 + kB);
    float em1 = __expf(Lc1 - Cj1 + kB);
    float invM = 1.f / Mst;
    float mm = mbuf[t];
    float nv0 = (P0 * invM) * em0;
    float nv1 = (P1 * invM) * em1;
    float oldq0 = (a0 * invM) * 0x1p102f;
    float oldq1 = (a1 * invM) * 0x1p102f;
    a0 = mm * nv0 + (1.f - mm) * oldq0;
    a1 = mm * nv1 + (1.f - mm) * oldq1;
    els[l] = a0; els[l + 64] = a1;   // in-order LDS per wave: reads above got old data
    S += __logf(Mst) - kB;
    Mst = fmaxf(a0, a1);
    #pragma unroll
    for (int off = 32; off; off >>= 1) Mst = fmaxf(Mst, __shfl_xor(Mst, off));
    Lc0 = Lp0; Lc1 = Lp1;
  }

  float s0 = a0, s1 = a1;
  #pragma unroll
  for (int off = 32; off; off >>= 1) {
    s0 += __shfl_xor(s0, off);
    s1 += __shfl_xor(s1, off);
  }
  if (l == 0) bv[b] = S + __logf(s0 + s1);
}

// ---------------- k5: out = -sum_b bv[b] ----------------
__global__ __launch_bounds__(256) void k5_sum(const float* __restrict__ bv,
                                              float* __restrict__ out) {
  int t = threadIdx.x;
  float s = bv[t] + bv[t + 256];
  #pragma unroll
  for (int off = 32; off; off >>= 1) s += __shfl_xor(s, off);
  __shared__ float wsm[4];
  if ((t & 63) == 0) wsm[t >> 6] = s;
  __syncthreads();
  if (t == 0) out[0] = -(wsm[0] + wsm[1] + wsm[2] + wsm[3]);
}

extern "C" void kernel_launch(void* const* d_in, const int* in_sizes, int n_in,
                              void* d_out, int out_size, void* d_ws, size_t ws_size,
                              hipStream_t stream) {
  const int*   words      = (const int*)d_in[0];
  const float* masks      = (const float*)d_in[1];
  const float* tparams    = (const float*)d_in[2];
  const float* tag_embed  = (const float*)d_in[3];
  const float* word_embed = (const float*)d_in[4];
  const float* transform  = (const float*)d_in[5];
  const float* correction = (const float*)d_in[6];

  float* ws     = (float*)d_ws;
  float* M2     = ws;                 // 16384
  float* A      = ws + 16384;         // 16384
  float* C      = ws + 32768;         // 128
  float* bv     = ws + 32896;         // 512
  float* pmaxb  = ws + 33408;         // 786*128 = 100608
  float* psumb  = ws + 134016;        // 100608
  float* logits = ws + 234624;        // 6432896  (total ~26.7 MB)

  hipLaunchKernelGGL(k1_m2,    dim3(128),    dim3(128), 0, stream, transform, tag_embed, M2);
  hipLaunchKernelGGL(k1b_a,    dim3(128),    dim3(64),  0, stream, tparams, A);
  hipLaunchKernelGGL(k2_logits,dim3(K2_NB),  dim3(256), 0, stream, word_embed, M2, correction, logits, pmaxb, psumb);
  hipLaunchKernelGGL(k3_c,     dim3(S_),     dim3(256), 0, stream, pmaxb, psumb, C);
  hipLaunchKernelGGL(k4_rec,   dim3(512),    dim3(64),  0, stream, words, masks, A, C, logits, bv);
  hipLaunchKernelGGL(k5_sum,   dim3(1),      dim3(256), 0, stream, bv, (float*)d_out);
}